// Round 5
// baseline (399.260 us; speedup 1.0000x reference)
//
#include <hip/hip_runtime.h>

// Problem constants (from reference setup_inputs)
#define BB 8
#define AA 100000
#define KK 80
#define MM 32
// K1 (anchor kernel) tiling
#define NB1 391             // ceil(AA / 256)
#define NB1_P 392           // padded stride for reg/np partials
// K2 (cls sweep) tiling
#define K2BLK 256           // blocks per image -> grid (256, 8) = 2048 blocks
#define K2STRIDE (K2BLK * 256)       // 65536 threads per image
#define TOTAL4 (AA * KK / 4)         // 2,000,000 float4 per image
// ALPHA = 0.25, GAMMA = 2.0 baked in below.
//
// r5: SPLIT KERNELS. r0-r4 history: atomics removed (r2's 186us was a
// serialized far-atomic chain on one 64B line), ILP deepened, tile swept —
// focal_main pinned at ~133us with VALUBusy ~56% and HBM 11%: structural
// stalls from the coupled phase1(IoU,divergent)/phase2(streaming) pipeline,
// not a resource roofline. K1 does anchors only; K2 is a barrier-free
// streaming sweep at forced 8 blocks/CU occupancy.

__device__ __forceinline__ float cls_term(float c, int code, int k) {
    float x   = __builtin_amdgcn_fmed3f(c, 1e-4f, 1.0f - 1e-4f); // clamp, 1 op
    float em  = __expf(-x);
    float u   = 1.0f + em;
    float s   = __logf(u);
    float p   = __builtin_amdgcn_rcpf(u);   // smooth path only: 1-ulp rcp OK
    float omp = 1.0f - p;
    bool use2 = (code >= 0) && (k != code);
    return use2 ? (0.75f * p * p * (x + s)) : (0.25f * omp * omp * s);
}

// All-negative-anchor term: bit-identical to cls_term's use2==false result.
__device__ __forceinline__ float neg_term(float c) {
    float x   = __builtin_amdgcn_fmed3f(c, 1e-4f, 1.0f - 1e-4f);
    float em  = __expf(-x);
    float u   = 1.0f + em;
    float s   = __logf(u);
    float p   = __builtin_amdgcn_rcpf(u);
    float omp = 1.0f - p;
    return 0.25f * omp * omp * s;
}

// ---- K1: per-anchor IoU / argmax / positive code / smooth-L1 partials ----
__global__ __launch_bounds__(256)
void focal_anchors(const float* __restrict__ reg,
                   const float* __restrict__ anc,
                   const float* __restrict__ ann,
                   int*   __restrict__ codes,      // [BB][AA]
                   float* __restrict__ reg_part_g, // [BB][NB1_P]
                   int*   __restrict__ np_part)    // [BB][NB1_P]
{
    const int blk = blockIdx.x;
    const int b   = blockIdx.y;
    const int t   = threadIdx.x;
    const int a   = blk * 256 + t;
    const bool act = (a < AA);           // last block: t < 160 active

    __shared__ float s_ann[MM * 5];
    __shared__ int   s_wnp[4];
    __shared__ float s_wrg[4];

    if (t < MM * 5) s_ann[t] = ann[b * MM * 5 + t];
    __syncthreads();

    int   code     = -1;
    float reg_part = 0.0f;
    int   pos      = 0;
    if (act) {
        const float4 av = ((const float4*)anc)[a];
        const float ax1 = av.x, ay1 = av.y, ax2 = av.z, ay2 = av.w;
        float best = -2.0f;           // any real iou (>= -1) beats this
        int   bidx = 0;
        const float a_area = (ax2 - ax1) * (ay2 - ay1);
        #pragma unroll
        for (int m = 0; m < MM; ++m) {
            float bx1 = s_ann[m * 5 + 0], by1 = s_ann[m * 5 + 1];
            float bx2 = s_ann[m * 5 + 2], by2 = s_ann[m * 5 + 3];
            float lab = s_ann[m * 5 + 4];
            float area  = (bx2 - bx1) * (by2 - by1);
            float iw    = fmaxf(fminf(ax2, bx2) - fmaxf(ax1, bx1), 0.0f);
            float ih    = fmaxf(fminf(ay2, by2) - fmaxf(ay1, by1), 0.0f);
            float inter = iw * ih;
            float ua    = fmaxf(a_area + area - inter, 1e-8f);
            float iou   = inter / ua;            // IEEE div: match XLA exactly
            if (lab == -1.0f) iou = -1.0f;
            if (iou > best) { best = iou; bidx = m; }  // strict > = first-argmax
        }
        if (best >= 0.5f) {
            pos  = 1;
            code = (int)s_ann[bidx * 5 + 4];
            float gx1 = s_ann[bidx * 5 + 0], gy1 = s_ann[bidx * 5 + 1];
            float gx2 = s_ann[bidx * 5 + 2], gy2 = s_ann[bidx * 5 + 3];
            float aw  = ax2 - ax1,  ah  = ay2 - ay1;
            float acx = ax1 + 0.5f * aw, acy = ay1 + 0.5f * ah;
            float gw  = gx2 - gx1,  gh  = gy2 - gy1;
            float gcx = gx1 + 0.5f * gw, gcy = gy1 + 0.5f * gh; // before clip!
            gw = fmaxf(gw, 1.0f); gh = fmaxf(gh, 1.0f);
            float tt0 = ((gcx - acx) / aw) / 0.1f;
            float tt1 = ((gcy - acy) / ah) / 0.1f;
            float tt2 = logf(gw / aw) / 0.2f;
            float tt3 = logf(gh / ah) / 0.2f;
            const float4 rv = ((const float4*)reg)[(size_t)b * AA + a];
            float d0 = fabsf(tt0 - rv.x);
            float d1 = fabsf(tt1 - rv.y);
            float d2 = fabsf(tt2 - rv.z);
            float d3 = fabsf(tt3 - rv.w);
            const float th = 1.0f / 9.0f, hb = 0.5f / 9.0f;
            reg_part  = (d0 <= th ? 4.5f * d0 * d0 : d0 - hb)
                      + (d1 <= th ? 4.5f * d1 * d1 : d1 - hb)
                      + (d2 <= th ? 4.5f * d2 * d2 : d2 - hb)
                      + (d3 <= th ? 4.5f * d3 * d3 : d3 - hb);
        }
    }
    if (act) codes[b * AA + a] = code;   // coalesced dword store, L2-hot for K2

    // wave-level aggregation of num_pos / reg_sum (no atomics anywhere)
    {
        unsigned long long bal = __ballot(pos != 0);
        int wnp = __popcll(bal);
        float wrg = reg_part;
        #pragma unroll
        for (int off = 32; off > 0; off >>= 1) wrg += __shfl_down(wrg, off, 64);
        if ((t & 63) == 0) { s_wnp[t >> 6] = wnp; s_wrg[t >> 6] = wrg; }
    }
    __syncthreads();
    if (t == 0) {
        np_part   [b * NB1_P + blk] = s_wnp[0] + s_wnp[1] + s_wnp[2] + s_wnp[3];
        reg_part_g[b * NB1_P + blk] = s_wrg[0] + s_wrg[1] + s_wrg[2] + s_wrg[3];
    }
}

// ---- K2: barrier-free streaming focal sweep over cls (the 64M-elem payload) ----
__global__ __launch_bounds__(256, 8)   // force <=64 VGPR -> 8 blocks/CU, one round
void focal_cls(const float* __restrict__ cls,
               const int*   __restrict__ codes,
               float* __restrict__ cls_part)       // [BB][K2BLK]
{
    const int b   = blockIdx.y;
    const int t   = threadIdx.x;
    const int gid = blockIdx.x * 256 + t;
    const float4* __restrict__ c4  = (const float4*)(cls + (size_t)b * ((size_t)AA * KK));
    const int*    __restrict__ cod = codes + b * AA;

    float part = 0.0f;

    auto process = [&](const float4 vv, int g) {
        unsigned q  = (unsigned)g / 20u;            // anchor (magic-div)
        unsigned k0 = ((unsigned)g - q * 20u) * 4u; // class index of vv.x
        int ca = cod[q];                            // CSE'd with batch load
        if (__ballot(ca >= 0) == 0ULL) {            // wave-uniform fast path
            part += neg_term(vv.x);
            part += neg_term(vv.y);
            part += neg_term(vv.z);
            part += neg_term(vv.w);
        } else {
            part += cls_term(vv.x, ca, (int)k0);
            part += cls_term(vv.y, ca, (int)k0 + 1);
            part += cls_term(vv.z, ca, (int)k0 + 2);
            part += cls_term(vv.w, ca, (int)k0 + 3);
        }
    };

    // 3 unguarded superchunks of 8 (indices 0..23: max g = 23*65536+65535
    // = 1,572,863 < 2,000,000) — 8 cls loads + 8 code loads in flight, then
    // compute; with 8 waves/SIMD the other waves' loads fly under compute.
    #pragma unroll 1
    for (int sc = 0; sc < 3; ++sc) {
        const int g0 = gid + sc * 8 * K2STRIDE;
        float4 v[8];
        #pragma unroll
        for (int j = 0; j < 8; ++j) v[j] = c4[g0 + j * K2STRIDE];
        #pragma unroll
        for (int j = 0; j < 8; ++j) process(v[j], g0 + j * K2STRIDE);
    }
    // guarded tail superchunk: indices 24..30 (31 is always out of range)
    {
        const int g0 = gid + 24 * K2STRIDE;
        float4 v[7];
        #pragma unroll
        for (int j = 0; j < 7; ++j) {
            int g = g0 + j * K2STRIDE;
            if (g < TOTAL4) v[j] = c4[g];
        }
        #pragma unroll
        for (int j = 0; j < 7; ++j) {
            int g = g0 + j * K2STRIDE;
            if (g < TOTAL4) process(v[j], g);   // ballot under divergence:
        }                                       // uniform among active lanes
    }

    // wave shuffle reduce, 4 partials through LDS, one plain store per block
    __shared__ float s_wred[4];
    #pragma unroll
    for (int off = 32; off > 0; off >>= 1) part += __shfl_down(part, off, 64);
    if ((t & 63) == 0) s_wred[t >> 6] = part;
    __syncthreads();
    if (t == 0)
        cls_part[b * K2BLK + blockIdx.x] = s_wred[0] + s_wred[1] + s_wred[2] + s_wred[3];
}

__global__ __launch_bounds__(256)
void focal_final(const float* __restrict__ ann,
                 const float* __restrict__ cls_part,
                 const float* __restrict__ reg_part,
                 const int*   __restrict__ np_part,
                 float* __restrict__ out)
{
    const int t    = threadIdx.x;
    const int lane = t & 63, wid = t >> 6;
    __shared__ double sd[4];
    __shared__ float  sf[4];
    __shared__ int    si[4];
    __shared__ float  s_c[BB], s_r[BB];

    for (int b = 0; b < BB; ++b) {
        double cd = (double)cls_part[b * K2BLK + t];   // exactly 256 slots
        float rf = 0.0f; int np = 0;
        for (int j = t; j < NB1; j += 256) {           // 391 slots
            rf += reg_part[b * NB1_P + j];
            np += np_part [b * NB1_P + j];
        }
        #pragma unroll
        for (int off = 32; off > 0; off >>= 1) {
            cd += __shfl_down(cd, off, 64);
            rf += __shfl_down(rf, off, 64);
            np += __shfl_down(np, off, 64);
        }
        if (lane == 0) { sd[wid] = cd; sf[wid] = rf; si[wid] = np; }
        __syncthreads();
        if (t == 0) {
            double cdt = sd[0] + sd[1] + sd[2] + sd[3];
            float  rft = sf[0] + sf[1] + sf[2] + sf[3];
            int    npt = si[0] + si[1] + si[2] + si[3];
            bool has = false;
            for (int m = 0; m < MM; ++m)
                has |= (ann[b * MM * 5 + m * 5 + 4] != -1.0f);
            float npf  = (float)npt;
            float ctot = (float)cdt / fmaxf(npf, 0.01f);
            float rtot = (npt > 0) ? (rft / fmaxf(npf * 4.0f, 1.0f)) : 0.0f;
            s_c[b] = has ? ctot : 0.0f;
            s_r[b] = has ? rtot : 0.0f;
        }
        __syncthreads();   // protects sd/sf/si reuse for next image
    }
    if (t == 0) {
        float c = 0.0f, r = 0.0f;
        for (int b = 0; b < BB; ++b) { c += s_c[b]; r += s_r[b]; }
        out[0] = c / (float)BB;
        out[1] = r / (float)BB;
    }
}

extern "C" void kernel_launch(void* const* d_in, const int* in_sizes, int n_in,
                              void* d_out, int out_size, void* d_ws, size_t ws_size,
                              hipStream_t stream) {
    const float* cls = (const float*)d_in[0];   // (B, A, K)
    const float* reg = (const float*)d_in[1];   // (B, A, 4)
    const float* anc = (const float*)d_in[2];   // (1, A, 4)
    const float* ann = (const float*)d_in[3];   // (B, M, 5)
    float* out = (float*)d_out;                 // [mean_cls, mean_reg]

    // Workspace: every slot written unconditionally before it is read ->
    // no memset, no atomics, poison-robust.
    int*   codes    = (int*)d_ws;                       // [BB][AA]      3.2 MB
    float* cls_part = (float*)(codes + (size_t)BB * AA);// [BB][K2BLK]
    float* reg_part = cls_part + BB * K2BLK;            // [BB][NB1_P]
    int*   np_part  = (int*)(reg_part + BB * NB1_P);    // [BB][NB1_P]

    dim3 g1(NB1, BB);                 // (391, 8): per-anchor assignment
    focal_anchors<<<g1, 256, 0, stream>>>(reg, anc, ann, codes, reg_part, np_part);

    dim3 g2(K2BLK, BB);               // (256, 8) = 2048 blocks = 1 machine round
    focal_cls<<<g2, 256, 0, stream>>>(cls, codes, cls_part);

    focal_final<<<1, 256, 0, stream>>>(ann, cls_part, reg_part, np_part, out);
}